// Round 6
// baseline (367.190 us; speedup 1.0000x reference)
//
#include <hip/hip_runtime.h>
#include <math.h>

// AdaptedMixer — Round 6:
//  - k1m/k6m: global_load_lds(16B) async staging (m97 structure), stride-32 LDS.
//  - k5a/k5c: 2 adjacent i-chains per thread (halved wave-steps, dwordx2 loads);
//             k5a chunk-product via dt-cumsum + endpoint exp2 (exact).
// B=2 S=2048 Dm=768 I=1536 N=16 R=48 K=4.  M = B*S = 4096.

static constexpr int S_LEN  = 2048;
static constexpr int DMODEL = 768;
static constexpr int ICH    = 1536;
static constexpr int NST    = 16;
static constexpr int MROWS  = 4096;   // B*S
static constexpr int NCH    = 32;     // scan chunks
static constexpr int CHS    = 64;     // steps per chunk

typedef _Float16 f16;
typedef f16 f16x8 __attribute__((ext_vector_type(8)));
typedef f16 f16x4 __attribute__((ext_vector_type(4)));
typedef f16 f16x2 __attribute__((ext_vector_type(2)));
typedef float f32x4 __attribute__((ext_vector_type(4)));

typedef __attribute__((address_space(3))) void lds_void;
typedef const __attribute__((address_space(1))) void glb_void;

__device__ __forceinline__ void glds16(f16* l, const f16* g) {
    // async global->LDS, 16B/lane; LDS dest = wave-uniform base + lane*16
    __builtin_amdgcn_global_load_lds((glb_void*)g, (lds_void*)l, 16, 0, 0);
}

__device__ __forceinline__ float silu_f(float x) {
    return x / (1.0f + __expf(-x));
}

// ---------------- cvt: fp32 -> fp16, 4 elems/thread
__global__ __launch_bounds__(256) void cvt_h(
    const float* __restrict__ s, f16* __restrict__ d)
{
    int i = (blockIdx.x * 256 + threadIdx.x) * 4;
    float4 v = *(const float4*)(s + i);
    f16x4 o = { (f16)v.x, (f16)v.y, (f16)v.z, (f16)v.w };
    *(f16x4*)(d + i) = o;
}

// ---------------- K1: in_proj fp16 MFMA GEMM [4096,768] @ [3072,768]^T, async staging
__global__ __launch_bounds__(256) void k1m(
    const f16* __restrict__ Xh,    // [4096][768]
    const f16* __restrict__ Wh,    // [3072][768]
    float* __restrict__ hidden,    // [M][I]
    float* __restrict__ sgate)     // [M][I] (silu applied)
{
    __shared__ __align__(16) f16 As[128 * 32];
    __shared__ __align__(16) f16 Bs[128 * 32];
    const int tid = threadIdx.x;
    const int lane = tid & 63, wave = tid >> 6;
    const int quad = lane >> 4, l16 = lane & 15;
    const int wm = wave & 1, wn = wave >> 1;
    const int m0 = blockIdx.x * 128, n0 = blockIdx.y * 128;
    const int l_row = lane >> 2, l_c8 = (lane & 3) * 8;

    const f16* Ag = Xh + (size_t)(m0 + wave * 16 + l_row) * 768 + l_c8;
    const f16* Bg = Wh + (size_t)(n0 + wave * 16 + l_row) * 768 + l_c8;
    f16* As0 = As + (wave * 16) * 32;
    f16* As1 = As + (64 + wave * 16) * 32;
    f16* Bs0 = Bs + (wave * 16) * 32;
    f16* Bs1 = Bs + (64 + wave * 16) * 32;

    f32x4 acc[4][4] = {};
    for (int k0 = 0; k0 < 768; k0 += 32) {
        __syncthreads();
        glds16(As0, Ag + k0);
        glds16(As1, Ag + (size_t)64 * 768 + k0);
        glds16(Bs0, Bg + k0);
        glds16(Bs1, Bg + (size_t)64 * 768 + k0);
        __syncthreads();
        f16x8 af[4], bf[4];
        #pragma unroll
        for (int mi = 0; mi < 4; ++mi)
            af[mi] = *(const f16x8*)&As[(wm * 64 + mi * 16 + l16) * 32 + quad * 8];
        #pragma unroll
        for (int ni = 0; ni < 4; ++ni)
            bf[ni] = *(const f16x8*)&Bs[(wn * 64 + ni * 16 + l16) * 32 + quad * 8];
        #pragma unroll
        for (int mi = 0; mi < 4; ++mi)
            #pragma unroll
            for (int ni = 0; ni < 4; ++ni)
                acc[mi][ni] = __builtin_amdgcn_mfma_f32_16x16x32_f16(
                    af[mi], bf[ni], acc[mi][ni], 0, 0, 0);
    }
    const bool isGate = (n0 >= ICH);
    float* outp = isGate ? sgate : hidden;
    const int e0 = (isGate ? (n0 - ICH) : n0) + wn * 64 + l16;
    #pragma unroll
    for (int mi = 0; mi < 4; ++mi) {
        #pragma unroll
        for (int ni = 0; ni < 4; ++ni) {
            #pragma unroll
            for (int r = 0; r < 4; ++r) {
                int m = m0 + wm * 64 + mi * 16 + quad * 4 + r;
                int e = e0 + ni * 16;
                float v = acc[mi][ni][r];
                if (isGate) v = silu_f(v);
                outp[(size_t)m * ICH + e] = v;
            }
        }
    }
}

// ---------------- K2: causal depthwise conv (K=4) + bias + silu, [M][I] layout
__global__ __launch_bounds__(256) void k2_conv(
    const float* __restrict__ hidden,  // [M][I]
    const float* __restrict__ conv_w,  // [I][4]
    const float* __restrict__ conv_b,  // [I]
    float* __restrict__ h)             // [M][I]
{
    int idx = blockIdx.x * 256 + threadIdx.x;      // over M * (I/4)
    int i4 = idx % 384;
    int m  = idx / 384;
    int s  = m & (S_LEN - 1);
    const float* base = hidden + (size_t)m * ICH + i4 * 4;
    const int c0 = i4 * 4;
    float4 wa = *(const float4*)(conv_w + (c0 + 0) * 4);
    float4 wb = *(const float4*)(conv_w + (c0 + 1) * 4);
    float4 wc = *(const float4*)(conv_w + (c0 + 2) * 4);
    float4 wd = *(const float4*)(conv_w + (c0 + 3) * 4);
    float4 bv = *(const float4*)(conv_b + c0);
    float4 z = {0.f, 0.f, 0.f, 0.f};
    float4 x0 = *(const float4*)(base);
    float4 x1 = (s >= 1) ? *(const float4*)(base - ICH)     : z;
    float4 x2 = (s >= 2) ? *(const float4*)(base - 2 * ICH) : z;
    float4 x3 = (s >= 3) ? *(const float4*)(base - 3 * ICH) : z;
    float4 r;
    r.x = bv.x + wa.x * x3.x + wa.y * x2.x + wa.z * x1.x + wa.w * x0.x;
    r.y = bv.y + wb.x * x3.y + wb.y * x2.y + wb.z * x1.y + wb.w * x0.y;
    r.z = bv.z + wc.x * x3.z + wc.y * x2.z + wc.z * x1.z + wc.w * x0.z;
    r.w = bv.w + wd.x * x3.w + wd.y * x2.w + wd.z * x1.w + wd.w * x0.w;
    r.x = silu_f(r.x); r.y = silu_f(r.y); r.z = silu_f(r.z); r.w = silu_f(r.w);
    *(float4*)(h + (size_t)m * ICH + i4 * 4) = r;
}

// ---------------- K3: x_proj GEMM: ssmp[m][e] += h[m][:] . xw[e][:], K-split x4 atomics
__global__ __launch_bounds__(256) void k3_xproj(
    const float* __restrict__ h,   // [M][I]
    const float* __restrict__ xw,  // [80][I]
    float* __restrict__ ssmp)      // [M][80], pre-zeroed
{
    __shared__ float4 As[64][5];   // [m][k4]
    __shared__ float4 Bs[80][5];   // [e][k4]
    const int tid = threadIdx.x;
    const int tm = tid >> 4;       // m group 0..15
    const int te = tid & 15;       // e lane 0..15
    const int m0 = blockIdx.x * 64;
    const int k_beg = blockIdx.y * 384;
    const int lrow = tid >> 2, lc4 = tid & 3;
    float4 acc[4][5] = {};
    for (int k0 = k_beg; k0 < k_beg + 384; k0 += 16) {
        As[lrow][lc4] = *(const float4*)(h + (size_t)(m0 + lrow) * ICH + k0 + lc4 * 4);
        for (int t = tid; t < 320; t += 256)
            Bs[t >> 2][t & 3] = *(const float4*)(xw + (size_t)(t >> 2) * ICH + k0 + (t & 3) * 4);
        __syncthreads();
        #pragma unroll
        for (int kk4 = 0; kk4 < 4; ++kk4) {
            float4 a[4], b[5];
            #pragma unroll
            for (int i = 0; i < 4; ++i) a[i] = As[tm + 16 * i][kk4];
            #pragma unroll
            for (int j = 0; j < 5; ++j) b[j] = Bs[te + 16 * j][kk4];
            #pragma unroll
            for (int i = 0; i < 4; ++i)
                #pragma unroll
                for (int j = 0; j < 5; ++j) {
                    acc[i][j].x += a[i].x * b[j].x; acc[i][j].y += a[i].y * b[j].y;
                    acc[i][j].z += a[i].z * b[j].z; acc[i][j].w += a[i].w * b[j].w;
                }
        }
        __syncthreads();
    }
    #pragma unroll
    for (int i = 0; i < 4; ++i) {
        int m = m0 + tm + 16 * i;
        #pragma unroll
        for (int j = 0; j < 5; ++j) {
            float v = acc[i][j].x + acc[i][j].y + acc[i][j].z + acc[i][j].w;
            atomicAdd(ssmp + (size_t)m * 80 + te + 16 * j, v);
        }
    }
}

// ---------------- K4: dt = softplus(ts @ dtw^T + b) via fp16 MFMA, K=48 padded to 64.
__global__ __launch_bounds__(256) void k4m(
    const float* __restrict__ ssmp,   // [M][80] (ts = cols 0..47)
    const float* __restrict__ dtw,    // [I][48]
    const float* __restrict__ dtb,    // [I]
    const float* __restrict__ alpha,  // [I]
    float* __restrict__ dt)           // [M][I]
{
    __shared__ __align__(16) f16 As[128 * 72];   // [row][72] (64 K + 8 pad)
    __shared__ __align__(16) f16 Bs[128 * 72];
    const int tid = threadIdx.x;
    const int lane = tid & 63, wave = tid >> 6;
    const int quad = lane >> 4, l16 = lane & 15;
    const int wm = wave & 1, wn = wave >> 1;
    const int m0 = blockIdx.x * 128, n0 = blockIdx.y * 128;
    const int srow = tid >> 1;          // 0..127
    const int shalf = tid & 1;          // 0..1 -> cols [0,24) or [24,48)

    {   // stage A (ts) and B (dtw), cvt to fp16, zero-pad cols 48..63
        const float* sa = ssmp + (size_t)(m0 + srow) * 80 + shalf * 24;
        const float* sb = dtw + (size_t)(n0 + srow) * 48 + shalf * 24;
        f16* da = &As[srow * 72 + shalf * 24];
        f16* db = &Bs[srow * 72 + shalf * 24];
        #pragma unroll
        for (int j = 0; j < 6; ++j) {
            float4 va = *(const float4*)(sa + 4 * j);
            float4 vb = *(const float4*)(sb + 4 * j);
            f16x4 oa = { (f16)va.x, (f16)va.y, (f16)va.z, (f16)va.w };
            f16x4 ob = { (f16)vb.x, (f16)vb.y, (f16)vb.z, (f16)vb.w };
            *(f16x4*)(da + 4 * j) = oa;
            *(f16x4*)(db + 4 * j) = ob;
        }
        if (shalf) {
            f16x8 z = {};
            *(f16x8*)&As[srow * 72 + 48] = z;
            *(f16x8*)&As[srow * 72 + 56] = z;
            *(f16x8*)&Bs[srow * 72 + 48] = z;
            *(f16x8*)&Bs[srow * 72 + 56] = z;
        }
    }
    __syncthreads();

    f32x4 acc[4][4] = {};
    #pragma unroll
    for (int ks = 0; ks < 2; ++ks) {
        f16x8 af[4], bf[4];
        #pragma unroll
        for (int mi = 0; mi < 4; ++mi)
            af[mi] = *(const f16x8*)&As[(wm * 64 + mi * 16 + l16) * 72 + ks * 32 + quad * 8];
        #pragma unroll
        for (int ni = 0; ni < 4; ++ni)
            bf[ni] = *(const f16x8*)&Bs[(wn * 64 + ni * 16 + l16) * 72 + ks * 32 + quad * 8];
        #pragma unroll
        for (int mi = 0; mi < 4; ++mi)
            #pragma unroll
            for (int ni = 0; ni < 4; ++ni)
                acc[mi][ni] = __builtin_amdgcn_mfma_f32_16x16x32_f16(
                    af[mi], bf[ni], acc[mi][ni], 0, 0, 0);
    }

    #pragma unroll
    for (int ni = 0; ni < 4; ++ni) {
        int e = n0 + wn * 64 + ni * 16 + l16;
        float bias = dtb[e];
        float al = alpha[e];
        #pragma unroll
        for (int mi = 0; mi < 4; ++mi) {
            #pragma unroll
            for (int r = 0; r < 4; ++r) {
                int m = m0 + wm * 64 + mi * 16 + quad * 4 + r;
                float x = acc[mi][ni][r] + bias;
                float sp = (x > 20.0f) ? x : __logf(1.0f + __expf(x));
                if ((m & (S_LEN - 1)) == S_LEN - 1) sp *= al;
                dt[(size_t)m * ICH + e] = sp;
            }
        }
    }
}

// ---------------- K5a: scan phase A — per-chunk summary, 2 chains/thread.
// grid (I/128, NCH, B), block 256 = 64 chain-pairs x 4 n-lanes
__global__ __launch_bounds__(256) void k5a_chunk(
    const float* __restrict__ dt,    // [M][I]
    const float* __restrict__ h,     // [M][I]
    const float* __restrict__ ssmp,  // [M][80]: B cols 48..63
    const float* __restrict__ A_log, // [I][16]
    float* __restrict__ PArr,        // [B*I*16][32]
    float* __restrict__ SfArr)       // [B*I*16][32]
{
    const int tid = threadIdx.x;
    const int n4 = tid & 3;
    const int il = tid >> 2;                 // 0..63
    const int i = blockIdx.x * 128 + il * 2; // chains i, i+1
    const int c = blockIdx.y;
    const int b = blockIdx.z;
    const int s0 = c * CHS;
    const float L2E = 1.44269504088896f;
    float4 al0 = *(const float4*)(A_log + i * NST + n4 * 4);
    float4 al1 = *(const float4*)(A_log + (i + 1) * NST + n4 * 4);
    float A0[4] = { -expf(al0.x) * L2E, -expf(al0.y) * L2E, -expf(al0.z) * L2E, -expf(al0.w) * L2E };
    float A1[4] = { -expf(al1.x) * L2E, -expf(al1.y) * L2E, -expf(al1.z) * L2E, -expf(al1.w) * L2E };
    float s0a[4] = {}, s1a[4] = {};
    float cdt0 = 0.f, cdt1 = 0.f;
    const float* dtp = dt + (size_t)(b * S_LEN + s0) * ICH + i;
    const float* hp  = h  + (size_t)(b * S_LEN + s0) * ICH + i;
    const float* Bp  = ssmp + (size_t)(b * S_LEN + s0) * 80 + 48 + n4 * 4;
    #pragma unroll 4
    for (int t = 0; t < CHS; ++t) {
        float2 dv = *(const float2*)(dtp + (size_t)t * ICH);
        float2 hv = *(const float2*)(hp  + (size_t)t * ICH);
        float4 Bv = *(const float4*)(Bp + (size_t)t * 80);
        cdt0 += dv.x; cdt1 += dv.y;
        float x0 = dv.x * hv.x, x1 = dv.y * hv.y;
        #pragma unroll
        for (int j = 0; j < 4; ++j) {
            float Bj = (&Bv.x)[j];
            float dA0 = exp2f(A0[j] * dv.x);
            float dA1 = exp2f(A1[j] * dv.y);
            s0a[j] = fmaf(dA0, s0a[j], x0 * Bj);
            s1a[j] = fmaf(dA1, s1a[j], x1 * Bj);
        }
    }
    size_t base0 = ((size_t)(b * ICH + i) * NST + n4 * 4) * NCH + c;
    size_t base1 = base0 + (size_t)NST * NCH;
    #pragma unroll
    for (int j = 0; j < 4; ++j) {
        PArr[base0 + (size_t)j * NCH]  = exp2f(A0[j] * cdt0);   // = prod dA (telescoped)
        PArr[base1 + (size_t)j * NCH]  = exp2f(A1[j] * cdt1);
        SfArr[base0 + (size_t)j * NCH] = s0a[j];
        SfArr[base1 + (size_t)j * NCH] = s1a[j];
    }
}

// ---------------- K5b: combine chunk summaries into carry-in per chunk
__global__ __launch_bounds__(256) void k5b_carry(
    const float* __restrict__ PArr,
    const float* __restrict__ SfArr,
    float* __restrict__ CIn)
{
    int idx = blockIdx.x * 256 + threadIdx.x;   // over B*I*16 = 49152
    size_t base = (size_t)idx * NCH;
    float carry = 0.f;
    #pragma unroll
    for (int c = 0; c < NCH; ++c) {
        CIn[base + c] = carry;
        carry = fmaf(PArr[base + c], carry, SfArr[base + c]);
    }
}

// ---------------- K5c: replay chunk with carry-in, emit y as fp16; 2 chains/thread
__global__ __launch_bounds__(256) void k5c_emit(
    const float* __restrict__ dt,    // [M][I]
    const float* __restrict__ h,     // [M][I]
    const float* __restrict__ sgate, // [M][I]
    const float* __restrict__ ssmp,  // [M][80]: B 48..63, C 64..79
    const float* __restrict__ A_log, // [I][16]
    const float* __restrict__ Dp,    // [I]
    const float* __restrict__ fg,    // [I]
    const float* __restrict__ CIn,   // [B*I*16][32]
    f16* __restrict__ yh)            // [M][I] fp16
{
    const int tid = threadIdx.x;
    const int n4 = tid & 3;
    const int il = tid >> 2;
    const int i = blockIdx.x * 128 + il * 2;
    const int c = blockIdx.y;
    const int b = blockIdx.z;
    const int s0 = c * CHS;
    const float L2E = 1.44269504088896f;
    float4 al0 = *(const float4*)(A_log + i * NST + n4 * 4);
    float4 al1 = *(const float4*)(A_log + (i + 1) * NST + n4 * 4);
    float A0[4] = { -expf(al0.x) * L2E, -expf(al0.y) * L2E, -expf(al0.z) * L2E, -expf(al0.w) * L2E };
    float A1[4] = { -expf(al1.x) * L2E, -expf(al1.y) * L2E, -expf(al1.z) * L2E, -expf(al1.w) * L2E };
    const float Dv0 = Dp[i], Dv1 = Dp[i + 1];
    const float fg0 = fg[i], fg1 = fg[i + 1];
    size_t cb0 = ((size_t)(b * ICH + i) * NST + n4 * 4) * NCH + c;
    size_t cb1 = cb0 + (size_t)NST * NCH;
    float st0[4], st1[4];
    #pragma unroll
    for (int j = 0; j < 4; ++j) {
        st0[j] = CIn[cb0 + (size_t)j * NCH];
        st1[j] = CIn[cb1 + (size_t)j * NCH];
    }
    const float* dtp = dt    + (size_t)(b * S_LEN + s0) * ICH + i;
    const float* hp  = h     + (size_t)(b * S_LEN + s0) * ICH + i;
    const float* gp  = sgate + (size_t)(b * S_LEN + s0) * ICH + i;
    const float* Bp  = ssmp + (size_t)(b * S_LEN + s0) * 80 + 48 + n4 * 4;
    const float* Cp  = Bp + 16;
    f16* yout = yh + (size_t)(b * S_LEN + s0) * ICH + i;
    const bool last_chunk = (c == NCH - 1);
    #pragma unroll 4
    for (int t = 0; t < CHS; ++t) {
        float2 dv = *(const float2*)(dtp + (size_t)t * ICH);
        float2 hv = *(const float2*)(hp  + (size_t)t * ICH);
        float4 Bv = *(const float4*)(Bp + (size_t)t * 80);
        float4 Cv = *(const float4*)(Cp + (size_t)t * 80);
        float x0 = dv.x * hv.x, x1 = dv.y * hv.y;
        float yp0 = 0.f, yp1 = 0.f;
        #pragma unroll
        for (int j = 0; j < 4; ++j) {
            float Bj = (&Bv.x)[j], Cj = (&Cv.x)[j];
            float dA0 = exp2f(A0[j] * dv.x);
            float dA1 = exp2f(A1[j] * dv.y);
            st0[j] = fmaf(dA0, st0[j], x0 * Bj);
            st1[j] = fmaf(dA1, st1[j], x1 * Bj);
            yp0 = fmaf(st0[j], Cj, yp0);
            yp1 = fmaf(st1[j], Cj, yp1);
        }
        yp0 += __shfl_xor(yp0, 1, 4);
        yp0 += __shfl_xor(yp0, 2, 4);
        yp1 += __shfl_xor(yp1, 1, 4);
        yp1 += __shfl_xor(yp1, 2, 4);
        if (n4 == 0) {
            float2 g = *(const float2*)(gp + (size_t)t * ICH);
            float y0 = fmaf(hv.x, Dv0, yp0) * g.x;
            float y1 = fmaf(hv.y, Dv1, yp1) * g.y;
            if (last_chunk && t == CHS - 1) { y0 *= fg0; y1 *= fg1; }
            f16x2 o = { (f16)y0, (f16)y1 };
            *(f16x2*)(yout + (size_t)t * ICH) = o;
        }
    }
}

// ---------------- K6: out_proj fp16 MFMA GEMM [4096,1536] @ [768,1536]^T, async staging
__global__ __launch_bounds__(256) void k6m(
    const f16* __restrict__ Yh,    // [4096][1536]
    const f16* __restrict__ Wh,    // [768][1536]
    float* __restrict__ out)       // [M][768]
{
    __shared__ __align__(16) f16 As[128 * 32];
    __shared__ __align__(16) f16 Bs[128 * 32];
    const int tid = threadIdx.x;
    const int lane = tid & 63, wave = tid >> 6;
    const int quad = lane >> 4, l16 = lane & 15;
    const int wm = wave & 1, wn = wave >> 1;
    const int m0 = blockIdx.x * 128, n0 = blockIdx.y * 128;
    const int l_row = lane >> 2, l_c8 = (lane & 3) * 8;

    const f16* Ag = Yh + (size_t)(m0 + wave * 16 + l_row) * ICH + l_c8;
    const f16* Bg = Wh + (size_t)(n0 + wave * 16 + l_row) * ICH + l_c8;
    f16* As0 = As + (wave * 16) * 32;
    f16* As1 = As + (64 + wave * 16) * 32;
    f16* Bs0 = Bs + (wave * 16) * 32;
    f16* Bs1 = Bs + (64 + wave * 16) * 32;

    f32x4 acc[4][4] = {};
    for (int k0 = 0; k0 < ICH; k0 += 32) {
        __syncthreads();
        glds16(As0, Ag + k0);
        glds16(As1, Ag + (size_t)64 * ICH + k0);
        glds16(Bs0, Bg + k0);
        glds16(Bs1, Bg + (size_t)64 * ICH + k0);
        __syncthreads();
        f16x8 af[4], bf[4];
        #pragma unroll
        for (int mi = 0; mi < 4; ++mi)
            af[mi] = *(const f16x8*)&As[(wm * 64 + mi * 16 + l16) * 32 + quad * 8];
        #pragma unroll
        for (int ni = 0; ni < 4; ++ni)
            bf[ni] = *(const f16x8*)&Bs[(wn * 64 + ni * 16 + l16) * 32 + quad * 8];
        #pragma unroll
        for (int mi = 0; mi < 4; ++mi)
            #pragma unroll
            for (int ni = 0; ni < 4; ++ni)
                acc[mi][ni] = __builtin_amdgcn_mfma_f32_16x16x32_f16(
                    af[mi], bf[ni], acc[mi][ni], 0, 0, 0);
    }
    #pragma unroll
    for (int mi = 0; mi < 4; ++mi) {
        #pragma unroll
        for (int ni = 0; ni < 4; ++ni) {
            #pragma unroll
            for (int r = 0; r < 4; ++r) {
                int m = m0 + wm * 64 + mi * 16 + quad * 4 + r;
                int d = n0 + wn * 64 + ni * 16 + l16;
                out[(size_t)m * DMODEL + d] = acc[mi][ni][r];
            }
        }
    }
}

extern "C" void kernel_launch(void* const* d_in, const int* in_sizes, int n_in,
                              void* d_out, int out_size, void* d_ws, size_t ws_size,
                              hipStream_t stream) {
    const float* X     = (const float*)d_in[0];
    const float* W1    = (const float*)d_in[1];
    const float* CW    = (const float*)d_in[2];
    const float* CB    = (const float*)d_in[3];
    const float* XW    = (const float*)d_in[4];
    const float* DTW   = (const float*)d_in[5];
    const float* DTB   = (const float*)d_in[6];
    const float* ALOG  = (const float*)d_in[7];
    const float* DD    = (const float*)d_in[8];
    const float* OW    = (const float*)d_in[9];
    const float* ALPHA = (const float*)d_in[10];
    const float* FG    = (const float*)d_in[11];
    float* out = (float*)d_out;

    float* ws = (float*)d_ws;
    const size_t NBI = (size_t)MROWS * ICH;        // 6,291,456
    float* hidden = ws;
    float* sgate  = hidden + NBI;
    float* hbuf   = sgate + NBI;
    float* dtbuf  = hbuf + NBI;
    float* ssmp   = dtbuf + NBI;                   // 4096*80
    // halves region R1: [Xh | W1h] before k5c, reused as yh after
    f16* R1  = (f16*)(ssmp + (size_t)MROWS * 80);
    f16* Xh  = R1;                                  // 4096*768
    f16* W1h = R1 + (size_t)MROWS * DMODEL;         // 3072*768
    f16* yh  = R1;                                  // 4096*1536 (overlays Xh|W1h)
    f16* OWh = R1 + NBI;                            // 768*1536, lives until k6
    // scan chunk summaries overlay dead hidden buffer
    const size_t SEG = (size_t)2 * ICH * NST * NCH; // 1,572,864
    float* PArr = hidden;
    float* SfA  = hidden + SEG;
    float* CIn  = hidden + 2 * SEG;

    hipMemsetAsync(ssmp, 0, (size_t)MROWS * 80 * sizeof(float), stream);
    cvt_h<<<dim3(3072), 256, 0, stream>>>(X,  Xh);
    cvt_h<<<dim3(2304), 256, 0, stream>>>(W1, W1h);
    cvt_h<<<dim3(1152), 256, 0, stream>>>(OW, OWh);
    k1m<<<dim3(32, 24), 256, 0, stream>>>(Xh, W1h, hidden, sgate);
    k2_conv<<<dim3((MROWS * 384) / 256), 256, 0, stream>>>(hidden, CW, CB, hbuf);
    k3_xproj<<<dim3(64, 4), 256, 0, stream>>>(hbuf, XW, ssmp);
    k4m<<<dim3(32, 12), 256, 0, stream>>>(ssmp, DTW, DTB, ALPHA, dtbuf);
    k5a_chunk<<<dim3(12, NCH, 2), 256, 0, stream>>>(dtbuf, hbuf, ssmp, ALOG, PArr, SfA);
    k5b_carry<<<dim3(192), 256, 0, stream>>>(PArr, SfA, CIn);
    k5c_emit<<<dim3(12, NCH, 2), 256, 0, stream>>>(dtbuf, hbuf, sgate, ssmp, ALOG, DD, FG, CIn, yh);
    k6m<<<dim3(32, 6), 256, 0, stream>>>(yh, OWh, out);
}